// Round 7
// baseline (123.011 us; speedup 1.0000x reference)
//
#include <hip/hip_runtime.h>
#include <hip/hip_bf16.h>

#define SEQ   28
#define BATCH 8192
#define NIN   28
#define HID   128
#define NOUT  10

// gate pre-scales folded into weights/bias at pack time:
// i,f,o rows scaled by -log2(e)  -> exp2(z) = e^{-x}  (sigmoid denom)
// g rows scaled by +2*log2(e)    -> exp2(z) = e^{2x}  (tanh)
#define SCL_SIG  (-1.4426950408889634f)
#define SCL_TANH (2.8853900817779268f)

typedef __bf16 bf16_t;
typedef __bf16 bf16x8 __attribute__((ext_vector_type(8)));
typedef float  f32x4  __attribute__((ext_vector_type(4)));
typedef float  f32x2  __attribute__((ext_vector_type(2)));

// XOR-swizzle for row-major [rows][128] bf16 tiles (256B rows).
__device__ __forceinline__ unsigned swz(unsigned row, unsigned byte_in_row) {
    return row * 256u + (byte_in_row ^ ((row & 7u) << 4));
}

// Half-step barrier: LDS-only drain (cross-wave traffic inside a step is LDS).
__device__ __forceinline__ void barrier_lds() {
    asm volatile("s_waitcnt lgkmcnt(0)\n\ts_barrier" ::: "memory");
}

// Pack {Whh0, Whh1, Wih1} [512][128] fp32 -> frag-linear bf16 with per-gate
// scaling. frag index (ks*32+nt)*64+lane, elem j: gate = nt*16+(lane&15),
// k = ks*32+(lane>>4)*8+j.
__global__ void pack_w_kernel(const float* __restrict__ Whh0, bf16_t* __restrict__ o0,
                              const float* __restrict__ Whh1, bf16_t* __restrict__ o1,
                              const float* __restrict__ Wih1, bf16_t* __restrict__ o2) {
    int idx = blockIdx.x * 256 + threadIdx.x;      // 0 .. 3*65536-1
    int mi = idx >> 16;
    int e  = idx & 65535;
    const float* W = (mi == 0) ? Whh0 : (mi == 1) ? Whh1 : Wih1;
    bf16_t*      o = (mi == 0) ? o0   : (mi == 1) ? o1   : o2;
    int j    = e & 7;
    int frag = e >> 3;
    int lane = frag & 63;
    int ksnt = frag >> 6;
    int nt = ksnt & 31, ks = ksnt >> 5;
    int gate = nt * 16 + (lane & 15);
    int k    = ks * 32 + ((lane >> 4) << 3) + j;
    float s  = ((gate >> 7) == 2) ? SCL_TANH : SCL_SIG;
    o[e] = (bf16_t)(W[gate * 128 + k] * s);
}

// Load one L0 x A-frag (fp32 X row, K padded 28->32) into bf16x8.
__device__ __forceinline__ bf16x8 load_x0(const float* __restrict__ X,
                                          int t, int rb, int m, int l15, int l4) {
    const float* base = X + ((size_t)(t * BATCH + rb + 16 * m + l15)) * NIN + l4 * 8;
    f32x4 lo = *(const f32x4*)base;
    f32x4 hi = {0.f, 0.f, 0.f, 0.f};
    if (l4 < 3) hi = *(const f32x4*)(base + 4);
    bf16x8 v;
    #pragma unroll
    for (int j = 0; j < 4; ++j) { v[j] = (bf16_t)lo[j]; v[4 + j] = (bf16_t)hi[j]; }
    return v;
}

// LSTM activation for one element: z = {zi,zf,zg,zo} pre-scaled gates,
// cr = carried cell state (updated). Returns h (bf16). 5 exp2 + 2 rcp.
__device__ __forceinline__ bf16_t act_elem(float z0, float z1, float z2, float z3,
                                           float& cr) {
    float Ei = __builtin_amdgcn_exp2f(z0);     // e^{-zi}
    float Ef = __builtin_amdgcn_exp2f(z1);     // e^{-zf}
    float Eg = __builtin_amdgcn_exp2f(z2);     // e^{2zg}
    float Eo = __builtin_amdgcn_exp2f(z3);     // e^{-zo}
    float ti = 1.0f + Ei, tf = 1.0f + Ef;
    float tg = 1.0f + Eg, to = 1.0f + Eo;
    float titg = ti * tg;
    float cn = fmaf(cr, titg, tf * (tg - 2.0f)) * __builtin_amdgcn_rcpf(tf * titg);
    cr = cn;
    float Ec = __builtin_amdgcn_exp2f(SCL_TANH * cn);   // e^{2cn}
    float hv = (Ec - 1.0f) * __builtin_amdgcn_rcpf(to * (1.0f + Ec));
    return (bf16_t)hv;
}

// One half-step of the m-skewed pipeline. MH = m-half receiving its h-MFMAs
// for step th; MT = 1-MH = m-half finishing step tt (trans + h-write), where
// tt = th-1 for MH=0 ("A"), tt = th for MH=1 ("B"). PAR = th&1 (compile-time
// so all LDS buffer selects are constant). Every barrier-to-barrier region
// contains MFMA-pipe work (hM of stream MH, xM of stream MT) AND VALU/trans
// work (activations of stream MT) -> both pipes stay fed.
template <int LAYER, int MH, int PAR>
__device__ __forceinline__ void half_step(
    int th, int rb, int tid, int w, int l15, int l4,
    unsigned char* smem,
    const float* __restrict__ X, const bf16_t* __restrict__ h1r,
    bf16_t* __restrict__ h1w,
    bf16x8 (&whh)[4][4], bf16x8 (&wih)[4][4],
    float (&bias)[4], float (&c)[2][4],
    bf16x8 (&x)[4][2], f32x4 (&acc)[2][4])
{
    constexpr int MT  = 1 - MH;
    constexpr int KS  = (LAYER == 0) ? 1 : 4;
    constexpr int TBP = (MH == 0) ? (PAR ^ 1) : PAR;
    unsigned char* bufR = smem + ((PAR ^ 1) << 13);  // h(th-1)
    unsigned char* bufW = smem + (TBP << 13);        // h(tt) write target
    const int  tt    = (MH == 0) ? (th - 1) : th;
    const bool do_tr = (MH == 1) || (th >= 1);       // tt >= 0

    barrier_lds();

    // ---- L0: stream h(th-1) rows [16MH,16MH+16) to h1 (written & barrier'd) ----
    if constexpr (LAYER == 0) {
        if (th >= 1) {
            int row = MH * 16 + (tid >> 5);
            int b8  = (tid & 31) * 8;
            f32x2 v = *(const f32x2*)(bufR + swz(row, b8));
            *(f32x2*)((unsigned char*)h1w + ((size_t)((th - 1) * BATCH + rb + row)) * 256 + b8) = v;
        }
    }

    // ---- ds_read ah: h(th-1) A-frags for rows of m=MH ----
    bf16x8 ah[4];
    #pragma unroll
    for (int ks = 0; ks < 4; ++ks)
        ah[ks] = *(const bf16x8*)(bufR + swz(16 * MH + l15, (ks * 32 + l4 * 8) * 2));

    // ---- interleave: trans(MT, tt) elements between hM(MH, th) ks-groups ----
    bf16_t hv[4];
    if (do_tr)
        hv[0] = act_elem(acc[MT][0][0], acc[MT][1][0], acc[MT][2][0], acc[MT][3][0], c[MT][0]);
    #pragma unroll
    for (int ks = 0; ks < 4; ++ks) {
        #pragma unroll
        for (int q = 0; q < 4; ++q)
            acc[MH][q] = __builtin_amdgcn_mfma_f32_16x16x32_bf16(
                ah[ks], whh[q][ks], acc[MH][q], 0, 0, 0);
        if (ks < 3 && do_tr)
            hv[ks + 1] = act_elem(acc[MT][0][ks + 1], acc[MT][1][ks + 1],
                                  acc[MT][2][ks + 1], acc[MT][3][ks + 1], c[MT][ks + 1]);
    }

    // ---- xM: acc[MT] = bias + Wih·x(tt+1)  (step tt+1 feed-forward part) ----
    if ((MH == 0) || (th < SEQ - 1)) {
        #pragma unroll
        for (int q = 0; q < 4; ++q) {
            f32x4 b = {bias[q], bias[q], bias[q], bias[q]};
            acc[MT][q] = b;
            #pragma unroll
            for (int ks = 0; ks < KS; ++ks)
                acc[MT][q] = __builtin_amdgcn_mfma_f32_16x16x32_bf16(
                    x[ks][MT], wih[q][ks], acc[MT][q], 0, 0, 0);
        }
    }

    // ---- deferred h(tt) writes (hide trans-chain latency under xM) ----
    if (do_tr) {
        #pragma unroll
        for (int r = 0; r < 4; ++r)
            *(bf16_t*)(bufW + swz(16 * MT + l4 * 4 + r, (16 * w + l15) * 2)) = hv[r];
    }

    // ---- x prefetch for (tt+2, MT) ----
    if (th < SEQ - 1 - MH) {
        if constexpr (LAYER == 0) {
            x[0][MT] = load_x0(X, tt + 2, rb, MT, l15, l4);
        } else {
            #pragma unroll
            for (int ks = 0; ks < 4; ++ks)
                x[ks][MT] = *(const bf16x8*)(h1r + ((size_t)((tt + 2) * BATCH + rb + 16 * MT + l15)) * HID + ks * 32 + l4 * 8);
        }
    }
}

// Fused 2-layer LSTM: one block = 32 batch rows through BOTH layers.
// 8 waves, 1 block/CU, m-half skewed pipeline with 2 LDS barriers per step.
__global__ __launch_bounds__(512, 2)
void lstm_fused_kernel(const float* __restrict__ Wih0,
                       const float* __restrict__ bih0, const float* __restrict__ bhh0,
                       const float* __restrict__ bih1, const float* __restrict__ bhh1,
                       const float* __restrict__ X,
                       const bf16_t* __restrict__ whhp0,
                       const bf16_t* __restrict__ whhp1,
                       const bf16_t* __restrict__ wihp1,
                       bf16_t* __restrict__ h1,
                       const float* __restrict__ Wlin, const float* __restrict__ blin,
                       float* __restrict__ out)
{
    __shared__ unsigned char smem[16384] __attribute__((aligned(16)));

    const int tid  = threadIdx.x;
    const int lane = tid & 63;
    const int w    = tid >> 6;
    const int l15  = lane & 15;
    const int l4   = lane >> 4;
    const int rb   = blockIdx.x * 32;

    bf16x8 whh[4][4], wih[4][4];
    float  bias[4];
    float  c[2][4];
    bf16x8 x[4][2];
    f32x4  acc[2][4];

    // ================= phase 0: layer 0 =================
    #pragma unroll
    for (int q = 0; q < 4; ++q)
        #pragma unroll
        for (int ks = 0; ks < 4; ++ks)
            whh[q][ks] = *(const bf16x8*)(whhp0 + ((size_t)((ks * 32 + (w + 8 * q)) * 64 + lane)) * 8);
    #pragma unroll
    for (int q = 0; q < 4; ++q) {
        int gate = 16 * w + 128 * q + l15;
        float s = (q == 2) ? SCL_TANH : SCL_SIG;
        #pragma unroll
        for (int j = 0; j < 8; ++j) {
            int k = l4 * 8 + j;
            wih[q][0][j] = (k < NIN) ? (bf16_t)(Wih0[gate * NIN + k] * s) : (bf16_t)0.0f;
        }
        bias[q] = (bih0[gate] + bhh0[gate]) * s;
        c[0][q] = 0.f; c[1][q] = 0.f;
    }
    // zero both h buffers (h(-1) = 0)
    for (int i = tid * 16; i < 16384; i += 512 * 16) {
        f32x4 z = {0.f, 0.f, 0.f, 0.f};
        *(f32x4*)(smem + i) = z;
    }
    // prologue: x(0,m0), x(0,m1); acc[0] = bias + Wih·x(0,m0); then x(1,m0)
    x[0][0] = load_x0(X, 0, rb, 0, l15, l4);
    x[0][1] = load_x0(X, 0, rb, 1, l15, l4);
    #pragma unroll
    for (int q = 0; q < 4; ++q) {
        f32x4 b = {bias[q], bias[q], bias[q], bias[q]};
        acc[0][q] = __builtin_amdgcn_mfma_f32_16x16x32_bf16(x[0][0], wih[q][0], b, 0, 0, 0);
    }
    x[0][0] = load_x0(X, 1, rb, 0, l15, l4);
    // A(0)'s top barrier makes the zero-init visible

    for (int t2 = 0; t2 < SEQ; t2 += 2) {
        half_step<0, 0, 0>(t2,     rb, tid, w, l15, l4, smem, X, nullptr, h1, whh, wih, bias, c, x, acc);
        half_step<0, 1, 0>(t2,     rb, tid, w, l15, l4, smem, X, nullptr, h1, whh, wih, bias, c, x, acc);
        half_step<0, 0, 1>(t2 + 1, rb, tid, w, l15, l4, smem, X, nullptr, h1, whh, wih, bias, c, x, acc);
        half_step<0, 1, 1>(t2 + 1, rb, tid, w, l15, l4, smem, X, nullptr, h1, whh, wih, bias, c, x, acc);
    }

    // ---- phase 0 epilogue: finish h(27,m1); store h(27) ----
    barrier_lds();   // h(27,m0) writes (B(27)) visible
    {
        int row = tid >> 5;                 // 0..15
        int b8  = (tid & 31) * 8;
        f32x2 v = *(const f32x2*)(smem + 8192 + swz(row, b8));   // buf1 = h(27)
        *(f32x2*)((unsigned char*)h1 + ((size_t)(27 * BATCH + rb + row)) * 256 + b8) = v;
    }
    {
        bf16_t hv[4];
        #pragma unroll
        for (int r = 0; r < 4; ++r)
            hv[r] = act_elem(acc[1][0][r], acc[1][1][r], acc[1][2][r], acc[1][3][r], c[1][r]);
        #pragma unroll
        for (int r = 0; r < 4; ++r)
            *(bf16_t*)(smem + 8192 + swz(16 + l4 * 4 + r, (16 * w + l15) * 2)) = hv[r];
    }
    barrier_lds();
    {
        int row = 16 + (tid >> 5);
        int b8  = (tid & 31) * 8;
        f32x2 v = *(const f32x2*)(smem + 8192 + swz(row, b8));
        *(f32x2*)((unsigned char*)h1 + ((size_t)(27 * BATCH + rb + row)) * 256 + b8) = v;
    }
    __syncthreads();   // full drain: h1 global stores visible before phase 1 reads

    // ================= phase 1: layer 1 =================
    #pragma unroll
    for (int q = 0; q < 4; ++q) {
        #pragma unroll
        for (int ks = 0; ks < 4; ++ks) {
            whh[q][ks] = *(const bf16x8*)(whhp1 + ((size_t)((ks * 32 + (w + 8 * q)) * 64 + lane)) * 8);
            wih[q][ks] = *(const bf16x8*)(wihp1 + ((size_t)((ks * 32 + (w + 8 * q)) * 64 + lane)) * 8);
        }
        int gate = 16 * w + 128 * q + l15;
        float s = (q == 2) ? SCL_TANH : SCL_SIG;
        bias[q] = (bih1[gate] + bhh1[gate]) * s;
        c[0][q] = 0.f; c[1][q] = 0.f;
    }
    // re-zero both h buffers
    for (int i = tid * 16; i < 16384; i += 512 * 16) {
        f32x4 z = {0.f, 0.f, 0.f, 0.f};
        *(f32x4*)(smem + i) = z;
    }
    // prologue: x(0) both halves from h1; acc[0] = bias + Wih1·x(0,m0); x(1,m0)
    #pragma unroll
    for (int ks = 0; ks < 4; ++ks) {
        x[ks][0] = *(const bf16x8*)(h1 + ((size_t)(rb + l15)) * HID + ks * 32 + l4 * 8);
        x[ks][1] = *(const bf16x8*)(h1 + ((size_t)(rb + 16 + l15)) * HID + ks * 32 + l4 * 8);
    }
    #pragma unroll
    for (int q = 0; q < 4; ++q) {
        f32x4 b = {bias[q], bias[q], bias[q], bias[q]};
        acc[0][q] = b;
        #pragma unroll
        for (int ks = 0; ks < 4; ++ks)
            acc[0][q] = __builtin_amdgcn_mfma_f32_16x16x32_bf16(x[ks][0], wih[q][ks], acc[0][q], 0, 0, 0);
    }
    #pragma unroll
    for (int ks = 0; ks < 4; ++ks)
        x[ks][0] = *(const bf16x8*)(h1 + ((size_t)(BATCH + rb + l15)) * HID + ks * 32 + l4 * 8);

    for (int t2 = 0; t2 < SEQ; t2 += 2) {
        half_step<1, 0, 0>(t2,     rb, tid, w, l15, l4, smem, nullptr, h1, nullptr, whh, wih, bias, c, x, acc);
        half_step<1, 1, 0>(t2,     rb, tid, w, l15, l4, smem, nullptr, h1, nullptr, whh, wih, bias, c, x, acc);
        half_step<1, 0, 1>(t2 + 1, rb, tid, w, l15, l4, smem, nullptr, h1, nullptr, whh, wih, bias, c, x, acc);
        half_step<1, 1, 1>(t2 + 1, rb, tid, w, l15, l4, smem, nullptr, h1, nullptr, whh, wih, bias, c, x, acc);
    }

    // ---- phase 1 epilogue: finish h2(27,m1) ----
    barrier_lds();
    {
        bf16_t hv[4];
        #pragma unroll
        for (int r = 0; r < 4; ++r)
            hv[r] = act_elem(acc[1][0][r], acc[1][1][r], acc[1][2][r], acc[1][3][r], c[1][r]);
        #pragma unroll
        for (int r = 0; r < 4; ++r)
            *(bf16_t*)(smem + 8192 + swz(16 + l4 * 4 + r, (16 * w + l15) * 2)) = hv[r];
    }
    barrier_lds();   // h2(27) complete in buf1

    // ---- head: pred = h2[27] @ W_lin^T + b_lin ----
    if (tid < 32 * NOUT) {
        int row = tid / NOUT, oc = tid % NOUT;
        const unsigned char* hf = smem + 8192;   // buf1 = h2(27)
        float s = blin[oc];
        #pragma unroll 8
        for (int k = 0; k < HID; ++k) {
            float h = (float)*(const bf16_t*)(hf + swz(row, k * 2));
            s += h * Wlin[oc * HID + k];
        }
        out[(size_t)(rb + row) * NOUT + oc] = s;
    }
}

extern "C" void kernel_launch(void* const* d_in, const int* in_sizes, int n_in,
                              void* d_out, int out_size, void* d_ws, size_t ws_size,
                              hipStream_t stream) {
    const float* X    = (const float*)d_in[0];
    const float* Wih0 = (const float*)d_in[1];
    const float* Whh0 = (const float*)d_in[2];
    const float* bih0 = (const float*)d_in[3];
    const float* bhh0 = (const float*)d_in[4];
    const float* Wih1 = (const float*)d_in[5];
    const float* Whh1 = (const float*)d_in[6];
    const float* bih1 = (const float*)d_in[7];
    const float* bhh1 = (const float*)d_in[8];
    const float* Wlin = (const float*)d_in[9];
    const float* blin = (const float*)d_in[10];
    float* out = (float*)d_out;

    unsigned char* ws = (unsigned char*)d_ws;
    bf16_t* h1    = (bf16_t*)(ws);                       // 58,720,256 B
    bf16_t* whhp0 = (bf16_t*)(ws + 58720256);            //    131,072 B
    bf16_t* whhp1 = (bf16_t*)(ws + 58851328);            //    131,072 B
    bf16_t* wihp1 = (bf16_t*)(ws + 58982400);            //    131,072 B

    pack_w_kernel<<<dim3(768), dim3(256), 0, stream>>>(Whh0, whhp0, Whh1, whhp1, Wih1, wihp1);

    lstm_fused_kernel<<<dim3(256), dim3(512), 0, stream>>>(
        Wih0, bih0, bhh0, bih1, bhh1, X, whhp0, whhp1, wihp1, h1,
        Wlin, blin, out);
}

// Round 8
// 119.296 us; speedup vs baseline: 1.0311x; 1.0311x over previous
//
#include <hip/hip_runtime.h>
#include <hip/hip_bf16.h>

#define SEQ   28
#define BATCH 8192
#define NIN   28
#define HID   128
#define NOUT  10

// gate pre-scales folded into weights/bias at pack time:
// i,f,o rows scaled by -log2(e)  -> exp2(z) = e^{-x}  (sigmoid denom)
// g rows scaled by +2*log2(e)    -> exp2(z) = e^{2x}  (tanh)
#define SCL_SIG  (-1.4426950408889634f)
#define SCL_TANH (2.8853900817779268f)

typedef __bf16 bf16_t;
typedef __bf16 bf16x8 __attribute__((ext_vector_type(8)));
typedef float  f32x4  __attribute__((ext_vector_type(4)));

// XOR-swizzle for row-major [rows][128] bf16 tiles (256B rows).
__device__ __forceinline__ unsigned swz(unsigned row, unsigned byte_in_row) {
    return row * 256u + (byte_in_row ^ ((row & 7u) << 4));
}

// Per-step barrier: LDS-only drain (cross-wave traffic inside a step is LDS).
__device__ __forceinline__ void barrier_lds() {
    asm volatile("s_waitcnt lgkmcnt(0)\n\ts_barrier" ::: "memory");
}

// Pack {Whh0, Whh1, Wih1} [512][128] fp32 -> frag-linear bf16 with per-gate
// scaling. frag index (ks*32+nt)*64+lane, elem j: gate = nt*16+(lane&15),
// k = ks*32+(lane>>4)*8+j.
__global__ void pack_w_kernel(const float* __restrict__ Whh0, bf16_t* __restrict__ o0,
                              const float* __restrict__ Whh1, bf16_t* __restrict__ o1,
                              const float* __restrict__ Wih1, bf16_t* __restrict__ o2) {
    int idx = blockIdx.x * 256 + threadIdx.x;      // 0 .. 3*65536-1
    int mi = idx >> 16;
    int e  = idx & 65535;
    const float* W = (mi == 0) ? Whh0 : (mi == 1) ? Whh1 : Wih1;
    bf16_t*      o = (mi == 0) ? o0   : (mi == 1) ? o1   : o2;
    int j    = e & 7;
    int frag = e >> 3;
    int lane = frag & 63;
    int ksnt = frag >> 6;
    int nt = ksnt & 31, ks = ksnt >> 5;
    int gate = nt * 16 + (lane & 15);
    int k    = ks * 32 + ((lane >> 4) << 3) + j;
    float s  = ((gate >> 7) == 2) ? SCL_TANH : SCL_SIG;
    o[e] = (bf16_t)(W[gate * 128 + k] * s);
}

// Load one L0 x A-frag (fp32 X row, K padded 28->32) into bf16x8.
__device__ __forceinline__ bf16x8 load_x0(const float* __restrict__ X,
                                          int t, int rb, int m, int l15, int l4) {
    const float* base = X + ((size_t)(t * BATCH + rb + 16 * m + l15)) * NIN + l4 * 8;
    f32x4 lo = *(const f32x4*)base;
    f32x4 hi = {0.f, 0.f, 0.f, 0.f};
    if (l4 < 3) hi = *(const f32x4*)(base + 4);
    bf16x8 v;
    #pragma unroll
    for (int j = 0; j < 4; ++j) { v[j] = (bf16_t)lo[j]; v[4 + j] = (bf16_t)hi[j]; }
    return v;
}

// One LSTM step, overlap-structured (round-6 validated schedule):
//   barrier; [L0: stream h(t-1)->h1]; ds_read h(t-1); h-MFMA into accIn;
//   per m-slice: {vectorized trans(t) from accIn[m]  ||  x-MFMA(t+1) into
//   accOut[m]}; issue x(t+2) loads.
// Activation arithmetic is written as f32x4 ext-vector ops so hipcc emits
// v_pk_{add,mul,fma}_f32 (2 f32/lane/instr) for every non-trans op; exp2/rcp
// remain scalar per component (no packed transcendentals on CDNA4). Per-
// element math is bitwise identical to the scalar form.
template <int LAYER>
__device__ __forceinline__ void step_v2(
    int t, int rb, int tid, int w, int l15, int l4,
    unsigned char* smem,
    const float* __restrict__ X, const bf16_t* __restrict__ h1r,
    bf16_t* __restrict__ h1w,
    bf16x8 (&whh)[4][4], bf16x8 (&wih)[4][4],
    f32x4 (&biasv)[4], f32x4 (&c)[2],
    bf16x8 (&x)[4][2],
    f32x4 (&accIn)[2][4], f32x4 (&accOut)[2][4])
{
    constexpr int KS = (LAYER == 0) ? 1 : 4;
    unsigned char* hb = smem + ((~t & 1) << 13);   // holds h(t-1)
    unsigned char* hn = smem + ((t & 1) << 13);    // receives h(t)

    barrier_lds();   // all waves' h(t-1) LDS writes complete & visible

    // ---- L0: stream h(t-1) to global h1 (reads hb, now consistent) ----
    if constexpr (LAYER == 0) {
        if (t >= 1) {
            int row = tid >> 4, sc = tid & 15;
            f32x4 v = *(const f32x4*)(hb + swz(row, sc * 16));
            *(f32x4*)((unsigned char*)h1w + ((size_t)((t - 1) * BATCH + rb + row)) * 256 + sc * 16) = v;
        }
    }

    // ---- h-part MFMAs (ks-chunked: 4 a-frags live at a time) ----
    #pragma unroll
    for (int kc = 0; kc < 2; ++kc) {
        bf16x8 a0[2], a1[2];
        #pragma unroll
        for (int m = 0; m < 2; ++m) {
            a0[m] = *(const bf16x8*)(hb + swz(16 * m + l15, ((2 * kc) * 32 + l4 * 8) * 2));
            a1[m] = *(const bf16x8*)(hb + swz(16 * m + l15, ((2 * kc + 1) * 32 + l4 * 8) * 2));
        }
        #pragma unroll
        for (int m = 0; m < 2; ++m)
            #pragma unroll
            for (int q = 0; q < 4; ++q) {
                accIn[m][q] = __builtin_amdgcn_mfma_f32_16x16x32_bf16(
                    a0[m], whh[q][2 * kc], accIn[m][q], 0, 0, 0);
                accIn[m][q] = __builtin_amdgcn_mfma_f32_16x16x32_bf16(
                    a1[m], whh[q][2 * kc + 1], accIn[m][q], 0, 0, 0);
            }
    }

    // ---- per m-slice: vectorized activations(t) || x-part MFMAs for t+1 ----
    #pragma unroll
    for (int m = 0; m < 2; ++m) {
        // activations: 5 exp2 + 2 rcp per element; all non-trans ops f32x4
        f32x4 Ei, Ef, Eg, Eo;
        #pragma unroll
        for (int r = 0; r < 4; ++r) {
            Ei[r] = __builtin_amdgcn_exp2f(accIn[m][0][r]);   // e^{-zi}
            Ef[r] = __builtin_amdgcn_exp2f(accIn[m][1][r]);   // e^{-zf}
            Eg[r] = __builtin_amdgcn_exp2f(accIn[m][2][r]);   // e^{2zg}
            Eo[r] = __builtin_amdgcn_exp2f(accIn[m][3][r]);   // e^{-zo}
        }
        f32x4 ti = Ei + 1.0f, tf = Ef + 1.0f;
        f32x4 tg = Eg + 1.0f, to = Eo + 1.0f;
        f32x4 titg = ti * tg;
        f32x4 num  = c[m] * titg + tf * (tg - 2.0f);
        f32x4 den  = tf * titg;
        f32x4 rif;
        #pragma unroll
        for (int r = 0; r < 4; ++r) rif[r] = __builtin_amdgcn_rcpf(den[r]);
        f32x4 cn = num * rif;
        c[m] = cn;
        f32x4 e2 = cn * SCL_TANH;
        f32x4 Ec;
        #pragma unroll
        for (int r = 0; r < 4; ++r) Ec[r] = __builtin_amdgcn_exp2f(e2[r]);
        f32x4 dh = to * (Ec + 1.0f);
        f32x4 rh;
        #pragma unroll
        for (int r = 0; r < 4; ++r) rh[r] = __builtin_amdgcn_rcpf(dh[r]);
        f32x4 hvf = (Ec - 1.0f) * rh;
        #pragma unroll
        for (int r = 0; r < 4; ++r)
            *(bf16_t*)(hn + swz(16 * m + l4 * 4 + r, (16 * w + l15) * 2)) = (bf16_t)hvf[r];

        // x-part MFMAs for t+1 (independent of h(t); consumes x(t+1) regs)
        #pragma unroll
        for (int q = 0; q < 4; ++q) {
            accOut[m][q] = biasv[q];
            #pragma unroll
            for (int ks = 0; ks < KS; ++ks)
                accOut[m][q] = __builtin_amdgcn_mfma_f32_16x16x32_bf16(
                    x[ks][m], wih[q][ks], accOut[m][q], 0, 0, 0);
        }
    }

    // ---- issue x(t+2) loads into the just-freed x regs ----
    if (t + 2 < SEQ) {
        if constexpr (LAYER == 0) {
            #pragma unroll
            for (int m = 0; m < 2; ++m)
                x[0][m] = load_x0(X, t + 2, rb, m, l15, l4);
        } else {
            #pragma unroll
            for (int ks = 0; ks < 4; ++ks)
                #pragma unroll
                for (int m = 0; m < 2; ++m)
                    x[ks][m] = *(const bf16x8*)(h1r + ((size_t)((t + 2) * BATCH + rb + 16 * m + l15)) * HID + ks * 32 + l4 * 8);
        }
    }
}

// Fused 2-layer LSTM: one block = 32 batch rows through BOTH layers.
// 8 waves, 1 block/CU. Weights register-resident (frag-linear preload).
__global__ __launch_bounds__(512, 2)
void lstm_fused_kernel(const float* __restrict__ Wih0,
                       const float* __restrict__ bih0, const float* __restrict__ bhh0,
                       const float* __restrict__ bih1, const float* __restrict__ bhh1,
                       const float* __restrict__ X,
                       const bf16_t* __restrict__ whhp0,
                       const bf16_t* __restrict__ whhp1,
                       const bf16_t* __restrict__ wihp1,
                       bf16_t* __restrict__ h1,
                       const float* __restrict__ Wlin, const float* __restrict__ blin,
                       float* __restrict__ out)
{
    __shared__ unsigned char smem[16384] __attribute__((aligned(16)));

    const int tid  = threadIdx.x;
    const int lane = tid & 63;
    const int w    = tid >> 6;
    const int l15  = lane & 15;
    const int l4   = lane >> 4;
    const int rb   = blockIdx.x * 32;

    bf16x8 whh[4][4], wih[4][4];
    f32x4  biasv[4];
    f32x4  c[2];
    bf16x8 x[4][2];
    f32x4  accA[2][4], accB[2][4];

    // ================= phase 0: layer 0 =================
    #pragma unroll
    for (int q = 0; q < 4; ++q)
        #pragma unroll
        for (int ks = 0; ks < 4; ++ks)
            whh[q][ks] = *(const bf16x8*)(whhp0 + ((size_t)((ks * 32 + (w + 8 * q)) * 64 + lane)) * 8);
    #pragma unroll
    for (int q = 0; q < 4; ++q) {
        int gate = 16 * w + 128 * q + l15;
        float s = (q == 2) ? SCL_TANH : SCL_SIG;
        #pragma unroll
        for (int j = 0; j < 8; ++j) {
            int k = l4 * 8 + j;
            wih[q][0][j] = (k < NIN) ? (bf16_t)(Wih0[gate * NIN + k] * s) : (bf16_t)0.0f;
        }
        float b = (bih0[gate] + bhh0[gate]) * s;
        f32x4 bv = {b, b, b, b};
        biasv[q] = bv;
        c[0][q] = 0.f; c[1][q] = 0.f;   // (c zero-init via components below)
    }
    {
        f32x4 z = {0.f, 0.f, 0.f, 0.f};
        c[0] = z; c[1] = z;
    }
    // zero both h buffers
    for (int i = tid * 16; i < 16384; i += 512 * 16) {
        f32x4 z = {0.f, 0.f, 0.f, 0.f};
        *(f32x4*)(smem + i) = z;
    }
    // accA = bias + x(0)-part; then prefetch x(1)
    #pragma unroll
    for (int m = 0; m < 2; ++m)
        x[0][m] = load_x0(X, 0, rb, m, l15, l4);
    #pragma unroll
    for (int m = 0; m < 2; ++m)
        #pragma unroll
        for (int q = 0; q < 4; ++q)
            accA[m][q] = __builtin_amdgcn_mfma_f32_16x16x32_bf16(
                x[0][m], wih[q][0], biasv[q], 0, 0, 0);
    #pragma unroll
    for (int m = 0; m < 2; ++m)
        x[0][m] = load_x0(X, 1, rb, m, l15, l4);
    // body(0)'s top barrier makes the zero-init visible

    for (int t = 0; t < SEQ; t += 2) {
        step_v2<0>(t,     rb, tid, w, l15, l4, smem, X, nullptr, h1,
                   whh, wih, biasv, c, x, accA, accB);
        step_v2<0>(t + 1, rb, tid, w, l15, l4, smem, X, nullptr, h1,
                   whh, wih, biasv, c, x, accB, accA);
    }

    // final h(27) -> h1, then full drain before phase 1
    barrier_lds();
    {
        int row = tid >> 4, sc = tid & 15;
        f32x4 v = *(const f32x4*)(smem + 8192 + swz(row, sc * 16));  // buf1 = h(27)
        *(f32x4*)((unsigned char*)h1 + ((size_t)(27 * BATCH + rb + row)) * 256 + sc * 16) = v;
    }
    __syncthreads();   // h1 global stores drained (vmcnt) before L1 reads

    // ================= phase 1: layer 1 =================
    #pragma unroll
    for (int q = 0; q < 4; ++q) {
        #pragma unroll
        for (int ks = 0; ks < 4; ++ks) {
            whh[q][ks] = *(const bf16x8*)(whhp1 + ((size_t)((ks * 32 + (w + 8 * q)) * 64 + lane)) * 8);
            wih[q][ks] = *(const bf16x8*)(wihp1 + ((size_t)((ks * 32 + (w + 8 * q)) * 64 + lane)) * 8);
        }
        int gate = 16 * w + 128 * q + l15;
        float s = (q == 2) ? SCL_TANH : SCL_SIG;
        float b = (bih1[gate] + bhh1[gate]) * s;
        f32x4 bv = {b, b, b, b};
        biasv[q] = bv;
    }
    {
        f32x4 z = {0.f, 0.f, 0.f, 0.f};
        c[0] = z; c[1] = z;
    }
    // re-zero both h buffers (L0 left h-state in them)
    for (int i = tid * 16; i < 16384; i += 512 * 16) {
        f32x4 z = {0.f, 0.f, 0.f, 0.f};
        *(f32x4*)(smem + i) = z;
    }
    // accA = bias + x(0)-part from h1; then prefetch x(1)
    #pragma unroll
    for (int ks = 0; ks < 4; ++ks)
        #pragma unroll
        for (int m = 0; m < 2; ++m)
            x[ks][m] = *(const bf16x8*)(h1 + ((size_t)(rb + 16 * m + l15)) * HID + ks * 32 + l4 * 8);
    #pragma unroll
    for (int m = 0; m < 2; ++m)
        #pragma unroll
        for (int q = 0; q < 4; ++q) {
            accA[m][q] = biasv[q];
            #pragma unroll
            for (int ks = 0; ks < 4; ++ks)
                accA[m][q] = __builtin_amdgcn_mfma_f32_16x16x32_bf16(
                    x[ks][m], wih[q][ks], accA[m][q], 0, 0, 0);
        }
    #pragma unroll
    for (int ks = 0; ks < 4; ++ks)
        #pragma unroll
        for (int m = 0; m < 2; ++m)
            x[ks][m] = *(const bf16x8*)(h1 + ((size_t)(BATCH + rb + 16 * m + l15)) * HID + ks * 32 + l4 * 8);
    // body(0)'s top barrier makes the re-zero visible

    for (int t = 0; t < SEQ; t += 2) {
        step_v2<1>(t,     rb, tid, w, l15, l4, smem, nullptr, h1, nullptr,
                   whh, wih, biasv, c, x, accA, accB);
        step_v2<1>(t + 1, rb, tid, w, l15, l4, smem, nullptr, h1, nullptr,
                   whh, wih, biasv, c, x, accB, accA);
    }
    barrier_lds();   // h2(27) in buf1 consistent

    // ---- epilogue: pred = h2[27] @ W_lin^T + b_lin ----
    if (tid < 32 * NOUT) {
        int row = tid / NOUT, oc = tid % NOUT;
        const unsigned char* hf = smem + 8192;   // buf1 = h2(27)
        float s = blin[oc];
        #pragma unroll 8
        for (int k = 0; k < HID; ++k) {
            float h = (float)*(const bf16_t*)(hf + swz(row, k * 2));
            s += h * Wlin[oc * HID + k];
        }
        out[(size_t)(rb + row) * NOUT + oc] = s;
    }
}

extern "C" void kernel_launch(void* const* d_in, const int* in_sizes, int n_in,
                              void* d_out, int out_size, void* d_ws, size_t ws_size,
                              hipStream_t stream) {
    const float* X    = (const float*)d_in[0];
    const float* Wih0 = (const float*)d_in[1];
    const float* Whh0 = (const float*)d_in[2];
    const float* bih0 = (const float*)d_in[3];
    const float* bhh0 = (const float*)d_in[4];
    const float* Wih1 = (const float*)d_in[5];
    const float* Whh1 = (const float*)d_in[6];
    const float* bih1 = (const float*)d_in[7];
    const float* bhh1 = (const float*)d_in[8];
    const float* Wlin = (const float*)d_in[9];
    const float* blin = (const float*)d_in[10];
    float* out = (float*)d_out;

    unsigned char* ws = (unsigned char*)d_ws;
    bf16_t* h1    = (bf16_t*)(ws);                       // 58,720,256 B
    bf16_t* whhp0 = (bf16_t*)(ws + 58720256);            //    131,072 B
    bf16_t* whhp1 = (bf16_t*)(ws + 58851328);            //    131,072 B
    bf16_t* wihp1 = (bf16_t*)(ws + 58982400);            //    131,072 B

    pack_w_kernel<<<dim3(768), dim3(256), 0, stream>>>(Whh0, whhp0, Whh1, whhp1, Wih1, wihp1);

    lstm_fused_kernel<<<dim3(256), dim3(512), 0, stream>>>(
        Wih0, bih0, bhh0, bih1, bhh1, X, whhp0, whhp1, wihp1, h1,
        Wlin, blin, out);
}